// Round 1
// baseline (114.534 us; speedup 1.0000x reference)
//
#include <hip/hip_runtime.h>
#include <cfloat>
#include <cstddef>

#define NBATCH 2
#define NPTS   5000
#define NF     64
#define NB     10      // bins = N / BIN_SIZE
#define BINSZ  500
#define TOPK   5
#define ROTCOLS 100    // MAX_NUM_BINS/2 columns in rotations

// ---------------------------------------------------------------------------
// Kernel A: per-point LSH bin + squared norm. One wave (64 lanes) per point.
// ---------------------------------------------------------------------------
__global__ __launch_bounds__(256) void bin_norm_k(const float* __restrict__ pts,
                                                  const float* __restrict__ rot,
                                                  int* __restrict__ bin_idx,
                                                  float* __restrict__ na) {
    int pt   = blockIdx.x * 4 + (threadIdx.x >> 6);   // 4 waves/block, 2500 blocks = 10000 pts
    int lane = threadIdx.x & 63;
    float p  = pts[(size_t)pt * NF + lane];
    float nn = p * p;
    float c0 = p * rot[lane * ROTCOLS + 0];
    float c1 = p * rot[lane * ROTCOLS + 1];
    float c2 = p * rot[lane * ROTCOLS + 2];
    float c3 = p * rot[lane * ROTCOLS + 3];
    float c4 = p * rot[lane * ROTCOLS + 4];
    #pragma unroll
    for (int off = 32; off > 0; off >>= 1) {
        nn += __shfl_xor(nn, off);
        c0 += __shfl_xor(c0, off);
        c1 += __shfl_xor(c1, off);
        c2 += __shfl_xor(c2, off);
        c3 += __shfl_xor(c3, off);
        c4 += __shfl_xor(c4, off);
    }
    if (lane == 0) {
        float c[5] = {c0, c1, c2, c3, c4};
        float bv = c[0]; int bi = 0;
        #pragma unroll
        for (int h = 1; h < 5; ++h) if (c[h] > bv) { bv = c[h]; bi = h; }
        #pragma unroll
        for (int h = 0; h < 5; ++h) if (-c[h] > bv) { bv = -c[h]; bi = h + 5; }
        bin_idx[pt] = bi;   // first-max wins, matches jnp.argmax
        na[pt] = nn;
    }
}

// ---------------------------------------------------------------------------
// Kernel B: stable counting sort of point indices by bin. One block per batch.
// Equivalent to stable argsort(bin_idx) chopped into NB groups of BINSZ.
// ---------------------------------------------------------------------------
__global__ __launch_bounds__(256) void sort_k(const int* __restrict__ bin_idx,
                                              int* __restrict__ order) {
    const int b = blockIdx.x;
    const int t = threadIdx.x;
    __shared__ int sh_bin[NPTS];
    __shared__ int sh_hist[256][NB];
    __shared__ int sh_start[NB + 1];
    for (int i = t; i < NPTS; i += 256) sh_bin[i] = bin_idx[b * NPTS + i];
    #pragma unroll
    for (int h = 0; h < NB; ++h) sh_hist[t][h] = 0;
    __syncthreads();
    const int CH = (NPTS + 255) / 256;            // 20
    const int i0 = t * CH;
    const int i1 = (i0 + CH < NPTS) ? (i0 + CH) : NPTS;
    for (int i = i0; i < i1; ++i) sh_hist[t][sh_bin[i]]++;
    __syncthreads();
    if (t < NB) {                                  // total per bin
        int tot = 0;
        for (int c = 0; c < 256; ++c) tot += sh_hist[c][t];
        sh_start[t + 1] = tot;
    }
    __syncthreads();
    if (t == 0) {                                  // exclusive prefix over bins
        sh_start[0] = 0;
        for (int h = 1; h <= NB; ++h) sh_start[h] += sh_start[h - 1];
    }
    __syncthreads();
    if (t < NB) {                                  // per-chunk running offsets
        int run = sh_start[t];
        for (int c = 0; c < 256; ++c) { int v = sh_hist[c][t]; sh_hist[c][t] = run; run += v; }
    }
    __syncthreads();
    for (int i = i0; i < i1; ++i) {                // stable placement
        int h = sh_bin[i];
        order[b * NPTS + sh_hist[t][h]++] = i;
    }
}

// ---------------------------------------------------------------------------
// Kernel C: per-group pairwise d^2 + top-5 + scatter.
// Grid: 20 groups x 8 row-blocks = 160 blocks of 256 threads (4 waves).
// Each lane owns one row (cached in 64 VGPRs); wave w handles cols
// [w*125, (w+1)*125) — LDS column reads are wave-uniform broadcasts (no
// bank conflicts). Per-row 4-way top-5 merge through LDS, then exp for
// the 5 winners only (exp is monotone in d^2, ties -> lower index, matching
// lax.top_k on the affinity).
// ---------------------------------------------------------------------------
__global__ __launch_bounds__(256) void pair_topk_k(const float* __restrict__ pts,
                                                   const float* __restrict__ na,
                                                   const int* __restrict__ order,
                                                   float* __restrict__ out) {
    const int bx  = blockIdx.x;
    const int g   = bx >> 3;        // 0..19
    const int rb  = bx & 7;         // 0..7 (row block of 64)
    const int b   = g / NB;
    const int grp = g % NB;
    const int r0  = rb * 64;
    const int tid = threadIdx.x;
    const int w   = tid >> 6;       // col partition 0..3
    const int lane = tid & 63;      // row within block

    __shared__ float sh_pts[BINSZ * NF];     // 128000 B
    __shared__ float sh_na[BINSZ];
    __shared__ int   sh_idx[BINSZ];
    __shared__ float sh_mv[4][64][TOPK];
    __shared__ int   sh_mi[4][64][TOPK];

    const int* ord = order + b * NPTS + grp * BINSZ;
    for (int i = tid; i < BINSZ; i += 256) sh_idx[i] = ord[i];
    __syncthreads();

    const float* pbase = pts + (size_t)b * NPTS * NF;
    float4* sp4 = (float4*)sh_pts;
    for (int q = tid; q < BINSZ * (NF / 4); q += 256) {
        int j = q >> 4, f4 = q & 15;
        sp4[q] = ((const float4*)(pbase + (size_t)sh_idx[j] * NF))[f4];
    }
    for (int i = tid; i < BINSZ; i += 256) sh_na[i] = na[b * NPTS + sh_idx[i]];
    __syncthreads();

    const int rr  = r0 + lane;
    const int rcl = (rr < BINSZ) ? rr : (BINSZ - 1);   // clamp; invalid rows never write
    float4 rowr[16];
    #pragma unroll
    for (int q = 0; q < 16; ++q) rowr[q] = sp4[rcl * 16 + q];
    const float na_r = sh_na[rcl];

    float tv[TOPK]; int ti[TOPK];
    #pragma unroll
    for (int s = 0; s < TOPK; ++s) { tv[s] = FLT_MAX; ti[s] = 0; }

    const int cbase = w * 125;
    for (int j = cbase; j < cbase + 125; ++j) {
        const float4* cp = sp4 + j * 16;
        float acc = 0.f;
        #pragma unroll
        for (int q = 0; q < 16; ++q) {
            float4 cc = cp[q];                 // broadcast across wave
            acc += rowr[q].x * cc.x;
            acc += rowr[q].y * cc.y;
            acc += rowr[q].z * cc.z;
            acc += rowr[q].w * cc.w;
        }
        float d2 = na_r - 2.f * acc + sh_na[j];
        if (d2 < tv[TOPK - 1]) {               // keep 5 smallest d2, stable
            tv[TOPK - 1] = d2; ti[TOPK - 1] = j;
            #pragma unroll
            for (int s = TOPK - 1; s > 0; --s) {
                if (tv[s] < tv[s - 1]) {
                    float fv = tv[s]; tv[s] = tv[s - 1]; tv[s - 1] = fv;
                    int   fi = ti[s]; ti[s] = ti[s - 1]; ti[s - 1] = fi;
                }
            }
        }
    }

    #pragma unroll
    for (int s = 0; s < TOPK; ++s) { sh_mv[w][lane][s] = tv[s]; sh_mi[w][lane][s] = ti[s]; }
    __syncthreads();

    if (tid < 64) {
        const int r = tid;
        if (r0 + r < BINSZ) {
            int h0 = 0, h1 = 0, h2 = 0, h3 = 0;
            const int src = sh_idx[r0 + r];
            float* orow = out + ((size_t)b * NPTS + src) * NPTS;
            #pragma unroll
            for (int s = 0; s < TOPK; ++s) {
                float v0 = sh_mv[0][r][h0];
                float v1 = sh_mv[1][r][h1];
                float v2 = sh_mv[2][r][h2];
                float v3 = sh_mv[3][r][h3];
                float best = v0; int bw = 0;
                if (v1 < best) { best = v1; bw = 1; }
                if (v2 < best) { best = v2; bw = 2; }
                if (v3 < best) { best = v3; bw = 3; }
                int j;
                if      (bw == 0) { j = sh_mi[0][r][h0]; h0++; }
                else if (bw == 1) { j = sh_mi[1][r][h1]; h1++; }
                else if (bw == 2) { j = sh_mi[2][r][h2]; h2++; }
                else              { j = sh_mi[3][r][h3]; h3++; }
                float dm  = sqrtf(fmaxf(best, 1e-6f));
                float val = expf(-0.1f * dm);
                orow[sh_idx[j]] = val;
            }
        }
    }
}

// ---------------------------------------------------------------------------
extern "C" void kernel_launch(void* const* d_in, const int* in_sizes, int n_in,
                              void* d_out, int out_size, void* d_ws, size_t ws_size,
                              hipStream_t stream) {
    const float* points = (const float*)d_in[0];
    const float* rot    = (const float*)d_in[1];
    float* out = (float*)d_out;

    int*   bin_idx = (int*)d_ws;                                          // 40 KB
    float* na      = (float*)((char*)d_ws + NBATCH * NPTS * sizeof(int)); // 40 KB
    int*   order   = (int*)((char*)d_ws + 2 * NBATCH * NPTS * sizeof(int)); // 40 KB

    // Output must be zeroed every call (poisoned once, never re-poisoned).
    hipMemsetAsync(d_out, 0, (size_t)out_size * sizeof(float), stream);

    bin_norm_k<<<(NBATCH * NPTS) / 4, 256, 0, stream>>>(points, rot, bin_idx, na);
    sort_k<<<NBATCH, 256, 0, stream>>>(bin_idx, order);
    pair_topk_k<<<NBATCH * NB * 8, 256, 0, stream>>>(points, na, order, out);
}